// Round 4
// baseline (3362.654 us; speedup 1.0000x reference)
//
#include <hip/hip_runtime.h>

#define DEV __device__ __forceinline__

typedef __bf16 bf16x8 __attribute__((ext_vector_type(8)));
typedef float floatx4 __attribute__((ext_vector_type(4)));
typedef unsigned short u16;

constexpr int NN    = 50000;   // nodes
constexpr int DEG   = 16;
constexpr int H2    = 128;

// ---- workspace byte offsets (total ~19.9 MB; hE lives inside d_out!) ----
constexpr size_t WS_WN    = 0;          // [64][128]  16384 B
constexpr size_t WS_WE    = 16384;      // [64][64]    8192 B
constexpr size_t WS_WIH_P = 24576;      // [512][128] 131072 B
constexpr size_t WS_WHH_P = 155648;
constexpr size_t WS_WR_P  = 286720;     // [64][128]
constexpr size_t WS_WIH_S = 303104;
constexpr size_t WS_WHH_S = 434176;
constexpr size_t WS_WR_S  = 565248;
constexpr size_t WS_WT_N  = 581632;     // [128][192]
constexpr size_t WS_WT_E  = 630784;     // [64][192]
constexpr size_t WS_BSUM_P= 655360;     // 512 f32
constexpr size_t WS_BSUM_S= 657408;
constexpr size_t WS_HN    = 659456;     // [50000][64] bf16 (6.4 MB)
constexpr size_t WS_AGGP  = 7059456;    // [50000][64] bf16
constexpr size_t WS_AGGS  = 13459456;   // end 19859456 B
// hE bf16 [800000] rows live at (u16*)edge_out_base + row*128 (first 128 B of
// each 256 B fp32 output slot). k_edge_out reads its own rows into LDS, syncs,
// then overwrites the same slots -> no cross-block race, zero extra ws.

DEV u16 f2bf(float x) {
  unsigned u = __builtin_bit_cast(unsigned, x);
  return (u16)((u + 0x7fffu + ((u >> 16) & 1u)) >> 16);
}
DEV bf16x8 ld8(const u16* p) { return *reinterpret_cast<const bf16x8*>(p); }
DEV floatx4 mfma16(bf16x8 a, bf16x8 b, floatx4 c) {
  return __builtin_amdgcn_mfma_f32_16x16x32_bf16(a, b, c, 0, 0, 0);
}
DEV floatx4 make4(float b) { floatx4 r = {b, b, b, b}; return r; }
DEV float sigf(float x) { return __builtin_amdgcn_rcpf(1.0f + __expf(-x)); }
// clamped exp: arg capped so e stays finite (<= e^60), keeping the fused
// sigmoid*tanh rcp-denominator free of inf-inf / 0*inf hazards.
DEV float expc(float x) { return __expf(fminf(x, 60.0f)); }
DEV bf16x8 relu8(bf16x8 a) {
  typedef u16 u16x8 __attribute__((ext_vector_type(8)));
  u16x8 u = __builtin_bit_cast(u16x8, a);
#pragma unroll
  for (int i = 0; i < 8; ++i) u[i] = (u[i] & 0x8000u) ? (u16)0 : u[i];
  return __builtin_bit_cast(bf16x8, u);
}

// ---------------- K0: weight conversion fp32->bf16 + bias sums ----------------
__global__ void k_prep(const float* Wn, const float* We,
                       const float* WihP, const float* WhhP, const float* WrP,
                       const float* WihS, const float* WhhS, const float* WrS,
                       const float* WtN, const float* WtE,
                       const float* bihP, const float* bhhP,
                       const float* bihS, const float* bhhS,
                       u16* wbf, float* bsumP, float* bsumS) {
  int idx = blockIdx.x * blockDim.x + threadIdx.x;
  if (idx < 327680) {
    const float* src; int rel;
    if      (idx <   8192) { src = Wn;   rel = idx; }
    else if (idx <  12288) { src = We;   rel = idx - 8192; }
    else if (idx <  77824) { src = WihP; rel = idx - 12288; }
    else if (idx < 143360) { src = WhhP; rel = idx - 77824; }
    else if (idx < 151552) { src = WrP;  rel = idx - 143360; }
    else if (idx < 217088) { src = WihS; rel = idx - 151552; }
    else if (idx < 282624) { src = WhhS; rel = idx - 217088; }
    else if (idx < 290816) { src = WrS;  rel = idx - 282624; }
    else if (idx < 315392) { src = WtN;  rel = idx - 290816; }
    else                   { src = WtE;  rel = idx - 315392; }
    wbf[idx] = f2bf(src[rel]);
  } else if (idx < 328704) {
    int j = idx - 327680;
    if (j < 512) bsumP[j] = bihP[j] + bhhP[j];
    else         bsumS[j - 512] = bihS[j - 512] + bhhS[j - 512];
  }
}

// ---------------- K1: hN = relu(node_vecs @ Wn.T + bn) -> bf16 ----------------
__global__ __launch_bounds__(256, 4) void k_pre_node(const float* xv, const float* bias,
                                                     const u16* Wbf, u16* outbf) {
  __shared__ __align__(16) u16 Xs[64 * 136];
  const int tid = threadIdx.x;
  const int base = blockIdx.x * 64;
#pragma unroll
  for (int j = 0; j < 8; ++j) {
    int flat = tid + j * 256;            // 64 rows x 32 float4
    int row = flat >> 5, c4 = flat & 31;
    int gr = base + row; if (gr >= NN) gr = NN - 1;
    float4 v = reinterpret_cast<const float4*>(xv + (size_t)gr * 128)[c4];
    ushort4 h; h.x = f2bf(v.x); h.y = f2bf(v.y); h.z = f2bf(v.z); h.w = f2bf(v.w);
    *reinterpret_cast<ushort4*>(&Xs[row * 136 + c4 * 4]) = h;
  }
  __syncthreads();
  const int wave = tid >> 6, lane = tid & 63, l16 = lane & 15, quad = lane >> 4;
  const int rt = wave;
  floatx4 acc[4];
#pragma unroll
  for (int ct = 0; ct < 4; ++ct) acc[ct] = make4(bias[ct * 16 + l16]);
#pragma unroll
  for (int kt = 0; kt < 4; ++kt) {
    bf16x8 a = ld8(&Xs[(rt * 16 + l16) * 136 + kt * 32 + quad * 8]);
#pragma unroll
    for (int ct = 0; ct < 4; ++ct) {
      bf16x8 b = ld8(Wbf + (ct * 16 + l16) * 128 + kt * 32 + quad * 8);
      acc[ct] = mfma16(a, b, acc[ct]);
    }
  }
#pragma unroll
  for (int ct = 0; ct < 4; ++ct)
#pragma unroll
    for (int r = 0; r < 4; ++r) {
      int row = base + rt * 16 + quad * 4 + r;
      if (row < NN) {
        float v = acc[ct][r]; v = v > 0.0f ? v : 0.0f;
        outbf[(size_t)row * 64 + ct * 16 + l16] = f2bf(v);
      }
    }
}

// ---------------- K2: hE = relu(edge_vecs @ We.T + be) -> bf16 ----------------
// Output rows go to stride-128 (u16) slots inside the edge_out region of d_out.
__global__ __launch_bounds__(256, 4) void k_pre_edge(const float* xv, const float* bias,
                                                     const u16* Wbf, u16* outbf) {
  __shared__ __align__(16) u16 Xs[64 * 72];
  const int tid = threadIdx.x;
  const size_t base = (size_t)blockIdx.x * 64;   // 12500 * 64 == 800000 exactly
#pragma unroll
  for (int j = 0; j < 4; ++j) {
    int flat = tid + j * 256;            // 64 rows x 16 float4
    int row = flat >> 4, c4 = flat & 15;
    float4 v = reinterpret_cast<const float4*>(xv + (base + row) * 64)[c4];
    ushort4 h; h.x = f2bf(v.x); h.y = f2bf(v.y); h.z = f2bf(v.z); h.w = f2bf(v.w);
    *reinterpret_cast<ushort4*>(&Xs[row * 72 + c4 * 4]) = h;
  }
  __syncthreads();
  const int wave = tid >> 6, lane = tid & 63, l16 = lane & 15, quad = lane >> 4;
  const int rt = wave;
  floatx4 acc[4];
#pragma unroll
  for (int ct = 0; ct < 4; ++ct) acc[ct] = make4(bias[ct * 16 + l16]);
#pragma unroll
  for (int kt = 0; kt < 2; ++kt) {
    bf16x8 a = ld8(&Xs[(rt * 16 + l16) * 72 + kt * 32 + quad * 8]);
#pragma unroll
    for (int ct = 0; ct < 4; ++ct) {
      bf16x8 b = ld8(Wbf + (ct * 16 + l16) * 64 + kt * 32 + quad * 8);
      acc[ct] = mfma16(a, b, acc[ct]);
    }
  }
#pragma unroll
  for (int ct = 0; ct < 4; ++ct)
#pragma unroll
    for (int r = 0; r < 4; ++r) {
      size_t row = base + rt * 16 + quad * 4 + r;
      float v = acc[ct][r]; v = v > 0.0f ? v : 0.0f;
      outbf[row * 128 + ct * 16 + l16] = f2bf(v);   // stride 128 u16 = 256 B
    }
}

// ---------------- K3: fused LSTM aggregator (32 nodes/block, 16 steps) --------
// 8 waves; wave w owns gate columns {g*128 + w*16 .. +16} for g in i,f,g,o.
// Double-buffered Xs/Hs -> ONE barrier per step. Gate math uses shared-rcp
// fusion. __launch_bounds__(512,4): 2 blocks/CU resident so one block's
// MFMA/VALU issue fills the other block's barrier-stall windows (~30% of the
// step at 1 block/CU). Regs ~270/wave incl. AGPRs, well under the 512 cap.
__global__ __launch_bounds__(512, 4) void k_lstm(
    const u16* hN, const u16* hE,
    const int* nidxP, const int* eidxP, const int* nidxS, const int* eidxS,
    const u16* WihP, const u16* WhhP, const float* bsumP, const u16* WrP, const float* brP, u16* aggP,
    const u16* WihS, const u16* WhhS, const float* bsumS, const u16* WrS, const float* brS, u16* aggS) {
  __shared__ __align__(16) u16 Xs[2][32 * 136];   // gathered [hN|hE], double-buffered
  __shared__ __align__(16) u16 Hs[2][32 * 136];   // h state bf16, double-buffered
  __shared__ int nidx_s[512], eidx_s[512];        // [32 nodes][16 steps]

  const bool s = (blockIdx.y != 0);
  const int* nidx = s ? nidxS : nidxP;
  const int* eidx = s ? eidxS : eidxP;
  const u16* Wih = s ? WihS : WihP;
  const u16* Whh = s ? WhhS : WhhP;
  const float* bsum = s ? bsumS : bsumP;
  const u16* Wr = s ? WrS : WrP;
  const float* br = s ? brS : brP;
  u16* aggOut = s ? aggS : aggP;

  const int tid = threadIdx.x;
  const int base = blockIdx.x * 32;
  {
    int g = base * 16 + tid;
    int vn = 0, ve = 0;
    if (g < NN * 16) { vn = nidx[g]; ve = eidx[g]; }
    nidx_s[tid] = vn; eidx_s[tid] = ve;
  }
  for (int j = tid; j < 32 * 136 / 2; j += 512) reinterpret_cast<unsigned*>(Hs[0])[j] = 0u;

  const int wave = tid >> 6, lane = tid & 63, l16 = lane & 15, quad = lane >> 4;

  // persistent weight B-fragments: [gate-class][k-tile]
  bf16x8 wx[4][4], wh[4][4];
  float bias[4];
#pragma unroll
  for (int g = 0; g < 4; ++g) {
    int gc = g * 128 + wave * 16 + l16;
    bias[g] = bsum[gc];
#pragma unroll
    for (int kt = 0; kt < 4; ++kt) {
      wx[g][kt] = ld8(Wih + gc * 128 + kt * 32 + quad * 8);
      wh[g][kt] = ld8(Whh + gc * 128 + kt * 32 + quad * 8);
    }
  }
  floatx4 cst[2] = {make4(0.0f), make4(0.0f)};
  __syncthreads();

  // per-thread staging slot: 32 rows x 16 chunks of 16B
  const int srow = tid >> 4, sub = tid & 15, seg = sub >> 3, soff = (sub & 7) * 8;
  const u16* sbase = seg ? hE : hN;
  const size_t sstride = seg ? 128 : 64;    // hE rows are stride-256B slots
  const int* sidx = seg ? eidx_s : nidx_s;

  // prologue: stage step 0 into Xs[0]
  {
    int r0 = sidx[srow * 16];
    uint4 v0 = *reinterpret_cast<const uint4*>(sbase + (size_t)r0 * sstride + soff);
    *reinterpret_cast<uint4*>(&Xs[0][srow * 136 + seg * 64 + soff]) = v0;
  }
  __syncthreads();

  for (int t = 0; t < DEG; ++t) {
    const int cur = t & 1, nxt = cur ^ 1;
    // issue-early: prefetch step t+1's gather into registers (clamped on last)
    int tn = (t + 1 < DEG) ? (t + 1) : t;
    int rn = sidx[srow * 16 + tn];
    uint4 vnext = *reinterpret_cast<const uint4*>(sbase + (size_t)rn * sstride + soff);

    floatx4 acc[4][2];
#pragma unroll
    for (int g = 0; g < 4; ++g) { acc[g][0] = make4(bias[g]); acc[g][1] = make4(bias[g]); }
    __builtin_amdgcn_s_setprio(1);
    // ---- half 0 (rows 0-15): x-part then h-part ----
#pragma unroll
    for (int kt = 0; kt < 4; ++kt) {
      bf16x8 a0 = ld8(&Xs[cur][l16 * 136 + kt * 32 + quad * 8]);
#pragma unroll
      for (int g = 0; g < 4; ++g) acc[g][0] = mfma16(a0, wx[g][kt], acc[g][0]);
    }
#pragma unroll
    for (int kt = 0; kt < 4; ++kt) {
      bf16x8 h0 = ld8(&Hs[cur][l16 * 136 + kt * 32 + quad * 8]);
#pragma unroll
      for (int g = 0; g < 4; ++g) acc[g][0] = mfma16(h0, wh[g][kt], acc[g][0]);
    }
    // ---- half 1 (rows 16-31): x-part then h-part ----
#pragma unroll
    for (int kt = 0; kt < 4; ++kt) {
      bf16x8 a1 = ld8(&Xs[cur][(16 + l16) * 136 + kt * 32 + quad * 8]);
#pragma unroll
      for (int g = 0; g < 4; ++g) acc[g][1] = mfma16(a1, wx[g][kt], acc[g][1]);
    }
#pragma unroll
    for (int kt = 0; kt < 4; ++kt) {
      bf16x8 h1 = ld8(&Hs[cur][(16 + l16) * 136 + kt * 32 + quad * 8]);
#pragma unroll
      for (int g = 0; g < 4; ++g) acc[g][1] = mfma16(h1, wh[g][kt], acc[g][1]);
    }
    __builtin_amdgcn_s_setprio(0);

    // gate math (registers only) + write h into NEXT buffer; no barrier before
    // this: wave's own acc dependencies gate it, siblings may still be in MFMA.
#pragma unroll
    for (int hh = 0; hh < 2; ++hh) {
      float hv[4];
#pragma unroll
      for (int rr = 0; rr < 4; ++rr) {
        float gi = acc[0][hh][rr], gf = acc[1][hh][rr];
        float gg = acc[2][hh][rr], go = acc[3][hh][rr];
        // c = sig(f)*c_old + sig(i)*tanh(g), shared-rcp fusion for the product
        float sf = sigf(gf);
        float ei = __expf(-gi);
        float eg = expc(-2.0f * gg);
        float r1 = __builtin_amdgcn_rcpf((1.0f + ei) * (1.0f + eg));
        float c  = __builtin_fmaf(sf, cst[hh][rr], (1.0f - eg) * r1);
        cst[hh][rr] = c;
        // h = sig(o)*tanh(c), same fusion
        float eo = __expf(-go);
        float ec = expc(-2.0f * c);
        float r2 = __builtin_amdgcn_rcpf((1.0f + eo) * (1.0f + ec));
        hv[rr] = (1.0f - ec) * r2;
      }
#pragma unroll
      for (int rp = 0; rp < 2; ++rp) {
        unsigned pk;
        asm("v_cvt_pk_bf16_f32 %0, %1, %2" : "=v"(pk) : "v"(hv[rp * 2]), "v"(hv[rp * 2 + 1]));
        const int r0 = hh * 16 + quad * 4 + rp * 2;
        Hs[nxt][r0 * 136 + wave * 16 + l16] = (u16)pk;
        Hs[nxt][(r0 + 1) * 136 + wave * 16 + l16] = (u16)(pk >> 16);
      }
    }

    // land the prefetched step-t+1 tile into the next Xs buffer
    if (t + 1 < DEG)
      *reinterpret_cast<uint4*>(&Xs[nxt][srow * 136 + seg * 64 + soff]) = vnext;
    __syncthreads();   // next-buffers (Hs, Xs) fully written before step t+1 reads
  }

  // readout: out = relu(relu(h) @ Wr.T + br), [32,64]; 8 tiles over 8 waves.
  // final h lives in Hs[0] (t=15 wrote nxt = 0).
  {
    const int rt = wave >> 2, ct = wave & 3;
    floatx4 acc = make4(br[ct * 16 + l16]);
#pragma unroll
    for (int kt = 0; kt < 4; ++kt) {
      bf16x8 a = relu8(ld8(&Hs[0][(rt * 16 + l16) * 136 + kt * 32 + quad * 8]));
      bf16x8 b = ld8(Wr + (ct * 16 + l16) * 128 + kt * 32 + quad * 8);
      acc = mfma16(a, b, acc);
    }
#pragma unroll
    for (int rr = 0; rr < 4; ++rr) {
      int row = base + rt * 16 + quad * 4 + rr;
      if (row < NN) {
        float v = acc[rr] > 0.0f ? acc[rr] : 0.0f;
        aggOut[(size_t)row * 64 + ct * 16 + l16] = f2bf(v);
      }
    }
  }
}

// ---------------- K4: node_out = relu([aggP|hN|aggS] @ Wt_n.T + bt_n) ---------
__global__ __launch_bounds__(256, 4) void k_node_out(
    const u16* aggP, const u16* hN, const u16* aggS,
    const u16* Wt, const float* bt, float* outp) {
  __shared__ __align__(16) u16 Xs[64 * 200];
  const int tid = threadIdx.x;
  const int base = blockIdx.x * 64;
  const u16* segp[3] = {aggP, hN, aggS};
#pragma unroll
  for (int seg = 0; seg < 3; ++seg)
#pragma unroll
    for (int j = 0; j < 2; ++j) {
      int flat = tid + j * 256;             // 64 rows x 8 chunks
      int row = flat >> 3, off = (flat & 7) * 8;
      int gr = base + row; if (gr >= NN) gr = NN - 1;
      uint4 v = *reinterpret_cast<const uint4*>(segp[seg] + (size_t)gr * 64 + off);
      *reinterpret_cast<uint4*>(&Xs[row * 200 + seg * 64 + off]) = v;
    }
  __syncthreads();
  const int wave = tid >> 6, lane = tid & 63, l16 = lane & 15, quad = lane >> 4;
  const int rt = wave;
  floatx4 acc[8];
#pragma unroll
  for (int ct = 0; ct < 8; ++ct) acc[ct] = make4(bt[ct * 16 + l16]);
#pragma unroll
  for (int kt = 0; kt < 6; ++kt) {
    bf16x8 a = ld8(&Xs[(rt * 16 + l16) * 200 + kt * 32 + quad * 8]);
#pragma unroll
    for (int ct = 0; ct < 8; ++ct) {
      bf16x8 b = ld8(Wt + (ct * 16 + l16) * 192 + kt * 32 + quad * 8);
      acc[ct] = mfma16(a, b, acc[ct]);
    }
  }
#pragma unroll
  for (int ct = 0; ct < 8; ++ct)
#pragma unroll
    for (int r = 0; r < 4; ++r) {
      int row = base + rt * 16 + quad * 4 + r;
      if (row < NN) {
        float v = acc[ct][r];
        __builtin_nontemporal_store(v > 0.0f ? v : 0.0f,
                                    &outp[(size_t)row * 128 + ct * 16 + l16]);
      }
    }
}

// ---------------- K5: edge_out = relu([hN[src]|hE|hN[dst]] @ Wt_e.T + bt_e) ---
// hE rows live in the FIRST 128 B of this block's own output slots; all reads
// complete (staged to LDS) before the __syncthreads, then we overwrite in place.
__global__ __launch_bounds__(256, 4) void k_edge_out(
    const u16* hN, const u16* hE, const int* esrc, const int* edst,
    const u16* Wt, const float* bt, float* outp) {
  __shared__ __align__(16) u16 Xs[64 * 200];
  __shared__ int idxs[128];
  const int tid = threadIdx.x;
  const size_t base = (size_t)blockIdx.x * 64;  // exact: 12500*64 == 800000
  if (tid < 64) idxs[tid] = esrc[base + tid];
  else if (tid < 128) idxs[tid] = edst[base + tid - 64];
  __syncthreads();
#pragma unroll
  for (int seg = 0; seg < 3; ++seg)
#pragma unroll
    for (int j = 0; j < 2; ++j) {
      int flat = tid + j * 256;
      int row = flat >> 3, off = (flat & 7) * 8;
      size_t grow;
      const u16* sp;
      if (seg == 0)      { grow = (size_t)idxs[row] * 64;       sp = hN; }
      else if (seg == 1) { grow = (base + row) * 128;           sp = hE; }
      else               { grow = (size_t)idxs[64 + row] * 64;  sp = hN; }
      uint4 v = *reinterpret_cast<const uint4*>(sp + grow + off);
      *reinterpret_cast<uint4*>(&Xs[row * 200 + seg * 64 + off]) = v;
    }
  __syncthreads();
  const int wave = tid >> 6, lane = tid & 63, l16 = lane & 15, quad = lane >> 4;
  const int rt = wave;
  floatx4 acc[4];
#pragma unroll
  for (int ct = 0; ct < 4; ++ct) acc[ct] = make4(bt[ct * 16 + l16]);
#pragma unroll
  for (int kt = 0; kt < 6; ++kt) {
    bf16x8 a = ld8(&Xs[(rt * 16 + l16) * 200 + kt * 32 + quad * 8]);
#pragma unroll
    for (int ct = 0; ct < 4; ++ct) {
      bf16x8 b = ld8(Wt + (ct * 16 + l16) * 192 + kt * 32 + quad * 8);
      acc[ct] = mfma16(a, b, acc[ct]);
    }
  }
#pragma unroll
  for (int ct = 0; ct < 4; ++ct)
#pragma unroll
    for (int r = 0; r < 4; ++r) {
      size_t row = base + rt * 16 + quad * 4 + r;
      float v = acc[ct][r];
      __builtin_nontemporal_store(v > 0.0f ? v : 0.0f,
                                  &outp[row * 64 + ct * 16 + l16]);
    }
}

extern "C" void kernel_launch(void* const* d_in, const int* in_sizes, int n_in,
                              void* d_out, int out_size, void* d_ws, size_t ws_size,
                              hipStream_t stream) {
  (void)in_sizes; (void)n_in; (void)out_size; (void)ws_size;
  const float* node_vecs = (const float*)d_in[0];
  const float* edge_vecs = (const float*)d_in[1];
  const int* pred_node_idx = (const int*)d_in[2];
  const int* pred_edge_idx = (const int*)d_in[3];
  const int* succ_node_idx = (const int*)d_in[4];
  const int* succ_edge_idx = (const int*)d_in[5];
  const int* edge_src = (const int*)d_in[6];
  const int* edge_dst = (const int*)d_in[7];
  const float* Wn = (const float*)d_in[8];
  const float* bn = (const float*)d_in[9];
  const float* We = (const float*)d_in[10];
  const float* be = (const float*)d_in[11];
  const float* Wih_p = (const float*)d_in[12];
  const float* Whh_p = (const float*)d_in[13];
  const float* bih_p = (const float*)d_in[14];
  const float* bhh_p = (const float*)d_in[15];
  const float* Wr_p = (const float*)d_in[16];
  const float* br_p = (const float*)d_in[17];
  const float* Wih_s = (const float*)d_in[18];
  const float* Whh_s = (const float*)d_in[19];
  const float* bih_s = (const float*)d_in[20];
  const float* bhh_s = (const float*)d_in[21];
  const float* Wr_s = (const float*)d_in[22];
  const float* br_s = (const float*)d_in[23];
  const float* Wt_n = (const float*)d_in[24];
  const float* bt_n = (const float*)d_in[25];
  const float* Wt_e = (const float*)d_in[26];
  const float* bt_e = (const float*)d_in[27];

  char* ws = (char*)d_ws;
  u16* wWn   = (u16*)(ws + WS_WN);
  u16* wWe   = (u16*)(ws + WS_WE);
  u16* wWihP = (u16*)(ws + WS_WIH_P);
  u16* wWhhP = (u16*)(ws + WS_WHH_P);
  u16* wWrP  = (u16*)(ws + WS_WR_P);
  u16* wWihS = (u16*)(ws + WS_WIH_S);
  u16* wWhhS = (u16*)(ws + WS_WHH_S);
  u16* wWrS  = (u16*)(ws + WS_WR_S);
  u16* wWtN  = (u16*)(ws + WS_WT_N);
  u16* wWtE  = (u16*)(ws + WS_WT_E);
  float* bsumP = (float*)(ws + WS_BSUM_P);
  float* bsumS = (float*)(ws + WS_BSUM_S);
  u16* hN   = (u16*)(ws + WS_HN);
  u16* aggP = (u16*)(ws + WS_AGGP);
  u16* aggS = (u16*)(ws + WS_AGGS);
  float* outN = (float*)d_out;
  float* outE = outN + (size_t)NN * 128;
  u16* hE = (u16*)outE;    // bf16 rows at stride 128 u16 inside edge_out slots

  k_prep<<<1284, 256, 0, stream>>>(Wn, We, Wih_p, Whh_p, Wr_p, Wih_s, Whh_s, Wr_s,
                                   Wt_n, Wt_e, bih_p, bhh_p, bih_s, bhh_s,
                                   (u16*)ws, bsumP, bsumS);
  k_pre_node<<<782, 256, 0, stream>>>(node_vecs, bn, wWn, hN);
  k_pre_edge<<<12500, 256, 0, stream>>>(edge_vecs, be, wWe, hE);
  dim3 g3(1563, 2, 1);
  k_lstm<<<g3, 512, 0, stream>>>(hN, hE,
                                 pred_node_idx, pred_edge_idx, succ_node_idx, succ_edge_idx,
                                 wWihP, wWhhP, bsumP, wWrP, br_p, aggP,
                                 wWihS, wWhhS, bsumS, wWrS, br_s, aggS);
  k_node_out<<<782, 256, 0, stream>>>(aggP, hN, aggS, wWtN, bt_n, outN);
  k_edge_out<<<12500, 256, 0, stream>>>(hN, hE, edge_src, edge_dst, wWtE, bt_e, outE);
}

// Round 5
// 1118.096 us; speedup vs baseline: 3.0075x; 3.0075x over previous
//
#include <hip/hip_runtime.h>

#define DEV __device__ __forceinline__

typedef __bf16 bf16x8 __attribute__((ext_vector_type(8)));
typedef float floatx4 __attribute__((ext_vector_type(4)));
typedef unsigned short u16;

constexpr int NN    = 50000;   // nodes
constexpr int DEG   = 16;
constexpr int H2    = 128;

// ---- workspace byte offsets (total ~19.9 MB; hE lives inside d_out!) ----
constexpr size_t WS_WN    = 0;          // [64][128]  16384 B
constexpr size_t WS_WE    = 16384;      // [64][64]    8192 B
constexpr size_t WS_WIH_P = 24576;      // [512][128] 131072 B
constexpr size_t WS_WHH_P = 155648;
constexpr size_t WS_WR_P  = 286720;     // [64][128]
constexpr size_t WS_WIH_S = 303104;
constexpr size_t WS_WHH_S = 434176;
constexpr size_t WS_WR_S  = 565248;
constexpr size_t WS_WT_N  = 581632;     // [128][192]
constexpr size_t WS_WT_E  = 630784;     // [64][192]
constexpr size_t WS_BSUM_P= 655360;     // 512 f32
constexpr size_t WS_BSUM_S= 657408;
constexpr size_t WS_HN    = 659456;     // [50000][64] bf16 (6.4 MB)
constexpr size_t WS_AGGP  = 7059456;    // [50000][64] bf16
constexpr size_t WS_AGGS  = 13459456;   // end 19859456 B
// hE bf16 [800000] rows live at (u16*)edge_out_base + row*128 (first 128 B of
// each 256 B fp32 output slot). k_edge_out reads its own rows into LDS, syncs,
// then overwrites the same slots -> no cross-block race, zero extra ws.

DEV u16 f2bf(float x) {
  unsigned u = __builtin_bit_cast(unsigned, x);
  return (u16)((u + 0x7fffu + ((u >> 16) & 1u)) >> 16);
}
DEV bf16x8 ld8(const u16* p) { return *reinterpret_cast<const bf16x8*>(p); }
DEV floatx4 mfma16(bf16x8 a, bf16x8 b, floatx4 c) {
  return __builtin_amdgcn_mfma_f32_16x16x32_bf16(a, b, c, 0, 0, 0);
}
DEV floatx4 make4(float b) { floatx4 r = {b, b, b, b}; return r; }
DEV float sigf(float x) { return __builtin_amdgcn_rcpf(1.0f + __expf(-x)); }
// clamped exp: arg capped so e stays finite (<= e^60), keeping the fused
// sigmoid*tanh rcp-denominator free of inf-inf / 0*inf hazards.
DEV float expc(float x) { return __expf(fminf(x, 60.0f)); }
DEV bf16x8 relu8(bf16x8 a) {
  typedef u16 u16x8 __attribute__((ext_vector_type(8)));
  u16x8 u = __builtin_bit_cast(u16x8, a);
#pragma unroll
  for (int i = 0; i < 8; ++i) u[i] = (u[i] & 0x8000u) ? (u16)0 : u[i];
  return __builtin_bit_cast(bf16x8, u);
}

// ---------------- K0: weight conversion fp32->bf16 + bias sums ----------------
__global__ void k_prep(const float* Wn, const float* We,
                       const float* WihP, const float* WhhP, const float* WrP,
                       const float* WihS, const float* WhhS, const float* WrS,
                       const float* WtN, const float* WtE,
                       const float* bihP, const float* bhhP,
                       const float* bihS, const float* bhhS,
                       u16* wbf, float* bsumP, float* bsumS) {
  int idx = blockIdx.x * blockDim.x + threadIdx.x;
  if (idx < 327680) {
    const float* src; int rel;
    if      (idx <   8192) { src = Wn;   rel = idx; }
    else if (idx <  12288) { src = We;   rel = idx - 8192; }
    else if (idx <  77824) { src = WihP; rel = idx - 12288; }
    else if (idx < 143360) { src = WhhP; rel = idx - 77824; }
    else if (idx < 151552) { src = WrP;  rel = idx - 143360; }
    else if (idx < 217088) { src = WihS; rel = idx - 151552; }
    else if (idx < 282624) { src = WhhS; rel = idx - 217088; }
    else if (idx < 290816) { src = WrS;  rel = idx - 282624; }
    else if (idx < 315392) { src = WtN;  rel = idx - 290816; }
    else                   { src = WtE;  rel = idx - 315392; }
    wbf[idx] = f2bf(src[rel]);
  } else if (idx < 328704) {
    int j = idx - 327680;
    if (j < 512) bsumP[j] = bihP[j] + bhhP[j];
    else         bsumS[j - 512] = bihS[j - 512] + bhhS[j - 512];
  }
}

// ---------------- K1: hN = relu(node_vecs @ Wn.T + bn) -> bf16 ----------------
// Epilogue: results staged to LDS (wave-local rows), then coalesced 16B stores.
__global__ __launch_bounds__(256, 4) void k_pre_node(const float* xv, const float* bias,
                                                     const u16* Wbf, u16* outbf) {
  __shared__ __align__(16) u16 Xs[64 * 136];
  const int tid = threadIdx.x;
  const int base = blockIdx.x * 64;
#pragma unroll
  for (int j = 0; j < 8; ++j) {
    int flat = tid + j * 256;            // 64 rows x 32 float4
    int row = flat >> 5, c4 = flat & 31;
    int gr = base + row; if (gr >= NN) gr = NN - 1;
    float4 v = reinterpret_cast<const float4*>(xv + (size_t)gr * 128)[c4];
    ushort4 h; h.x = f2bf(v.x); h.y = f2bf(v.y); h.z = f2bf(v.z); h.w = f2bf(v.w);
    *reinterpret_cast<ushort4*>(&Xs[row * 136 + c4 * 4]) = h;
  }
  __syncthreads();
  const int wave = tid >> 6, lane = tid & 63, l16 = lane & 15, quad = lane >> 4;
  const int rt = wave;
  floatx4 acc[4];
#pragma unroll
  for (int ct = 0; ct < 4; ++ct) acc[ct] = make4(bias[ct * 16 + l16]);
#pragma unroll
  for (int kt = 0; kt < 4; ++kt) {
    bf16x8 a = ld8(&Xs[(rt * 16 + l16) * 136 + kt * 32 + quad * 8]);
#pragma unroll
    for (int ct = 0; ct < 4; ++ct) {
      bf16x8 b = ld8(Wbf + (ct * 16 + l16) * 128 + kt * 32 + quad * 8);
      acc[ct] = mfma16(a, b, acc[ct]);
    }
  }
  // stage outputs back into Xs (wave rt reads/writes only rows rt*16..+16)
#pragma unroll
  for (int ct = 0; ct < 4; ++ct)
#pragma unroll
    for (int r = 0; r < 4; ++r) {
      float v = acc[ct][r]; v = v > 0.0f ? v : 0.0f;
      Xs[(rt * 16 + quad * 4 + r) * 136 + ct * 16 + l16] = f2bf(v);
    }
  __syncthreads();
  // coalesced copy-out: 8 consecutive lanes cover one 128B row
#pragma unroll
  for (int j = 0; j < 2; ++j) {
    int ch = tid + j * 256;              // 64 rows x 8 chunks of 16B
    int row = ch >> 3, off8 = (ch & 7) * 8;
    int gr = base + row;
    if (gr < NN) {
      uint4 v = *reinterpret_cast<const uint4*>(&Xs[row * 136 + off8]);
      *reinterpret_cast<uint4*>(outbf + (size_t)gr * 64 + off8) = v;
    }
  }
}

// ---------------- K2: hE = relu(edge_vecs @ We.T + be) -> bf16 ----------------
// Output rows go to stride-128 (u16) slots inside the edge_out region of d_out.
// Same LDS-staged coalesced store epilogue as K1.
__global__ __launch_bounds__(256, 4) void k_pre_edge(const float* xv, const float* bias,
                                                     const u16* Wbf, u16* outbf) {
  __shared__ __align__(16) u16 Xs[64 * 72];
  const int tid = threadIdx.x;
  const size_t base = (size_t)blockIdx.x * 64;   // 12500 * 64 == 800000 exactly
#pragma unroll
  for (int j = 0; j < 4; ++j) {
    int flat = tid + j * 256;            // 64 rows x 16 float4
    int row = flat >> 4, c4 = flat & 15;
    float4 v = reinterpret_cast<const float4*>(xv + (base + row) * 64)[c4];
    ushort4 h; h.x = f2bf(v.x); h.y = f2bf(v.y); h.z = f2bf(v.z); h.w = f2bf(v.w);
    *reinterpret_cast<ushort4*>(&Xs[row * 72 + c4 * 4]) = h;
  }
  __syncthreads();
  const int wave = tid >> 6, lane = tid & 63, l16 = lane & 15, quad = lane >> 4;
  const int rt = wave;
  floatx4 acc[4];
#pragma unroll
  for (int ct = 0; ct < 4; ++ct) acc[ct] = make4(bias[ct * 16 + l16]);
#pragma unroll
  for (int kt = 0; kt < 2; ++kt) {
    bf16x8 a = ld8(&Xs[(rt * 16 + l16) * 72 + kt * 32 + quad * 8]);
#pragma unroll
    for (int ct = 0; ct < 4; ++ct) {
      bf16x8 b = ld8(Wbf + (ct * 16 + l16) * 64 + kt * 32 + quad * 8);
      acc[ct] = mfma16(a, b, acc[ct]);
    }
  }
#pragma unroll
  for (int ct = 0; ct < 4; ++ct)
#pragma unroll
    for (int r = 0; r < 4; ++r) {
      float v = acc[ct][r]; v = v > 0.0f ? v : 0.0f;
      Xs[(rt * 16 + quad * 4 + r) * 72 + ct * 16 + l16] = f2bf(v);
    }
  __syncthreads();
#pragma unroll
  for (int j = 0; j < 2; ++j) {
    int ch = tid + j * 256;
    int row = ch >> 3, off8 = (ch & 7) * 8;
    uint4 v = *reinterpret_cast<const uint4*>(&Xs[row * 72 + off8]);
    *reinterpret_cast<uint4*>(outbf + (base + row) * 128 + off8) = v;
  }
}

// ---------------- K3: fused LSTM aggregator (32 nodes/block, 16 steps) --------
// 8 waves; wave w owns gate columns {g*128 + w*16 .. +16} for g in i,f,g,o.
// Double-buffered Xs/Hs -> ONE barrier per step. Gate math uses shared-rcp
// fusion. 2-deep gather prefetch: the load consumed at step t's end was issued
// at step t-1's start (~1.5 steps of latency cover). 1 block/CU (register-
// pinned: ~130 persistent weight frags/wave -> (512,2) is the only valid bound).
__global__ __launch_bounds__(512, 2) void k_lstm(
    const u16* hN, const u16* hE,
    const int* nidxP, const int* eidxP, const int* nidxS, const int* eidxS,
    const u16* WihP, const u16* WhhP, const float* bsumP, const u16* WrP, const float* brP, u16* aggP,
    const u16* WihS, const u16* WhhS, const float* bsumS, const u16* WrS, const float* brS, u16* aggS) {
  __shared__ __align__(16) u16 Xs[2][32 * 136];   // gathered [hN|hE], double-buffered
  __shared__ __align__(16) u16 Hs[2][32 * 136];   // h state bf16, double-buffered
  __shared__ int nidx_s[512], eidx_s[512];        // [32 nodes][16 steps]

  const bool s = (blockIdx.y != 0);
  const int* nidx = s ? nidxS : nidxP;
  const int* eidx = s ? eidxS : eidxP;
  const u16* Wih = s ? WihS : WihP;
  const u16* Whh = s ? WhhS : WhhP;
  const float* bsum = s ? bsumS : bsumP;
  const u16* Wr = s ? WrS : WrP;
  const float* br = s ? brS : brP;
  u16* aggOut = s ? aggS : aggP;

  const int tid = threadIdx.x;
  const int base = blockIdx.x * 32;
  {
    int g = base * 16 + tid;
    int vn = 0, ve = 0;
    if (g < NN * 16) { vn = nidx[g]; ve = eidx[g]; }
    nidx_s[tid] = vn; eidx_s[tid] = ve;
  }
  for (int j = tid; j < 32 * 136 / 2; j += 512) reinterpret_cast<unsigned*>(Hs[0])[j] = 0u;

  const int wave = tid >> 6, lane = tid & 63, l16 = lane & 15, quad = lane >> 4;

  // persistent weight B-fragments: [gate-class][k-tile]
  bf16x8 wx[4][4], wh[4][4];
  float bias[4];
#pragma unroll
  for (int g = 0; g < 4; ++g) {
    int gc = g * 128 + wave * 16 + l16;
    bias[g] = bsum[gc];
#pragma unroll
    for (int kt = 0; kt < 4; ++kt) {
      wx[g][kt] = ld8(Wih + gc * 128 + kt * 32 + quad * 8);
      wh[g][kt] = ld8(Whh + gc * 128 + kt * 32 + quad * 8);
    }
  }
  floatx4 cst[2] = {make4(0.0f), make4(0.0f)};
  __syncthreads();

  // per-thread staging slot: 32 rows x 16 chunks of 16B
  const int srow = tid >> 4, sub = tid & 15, seg = sub >> 3, soff = (sub & 7) * 8;
  const u16* sbase = seg ? hE : hN;
  const size_t sstride = seg ? 128 : 64;    // hE rows are stride-256B slots
  const int* sidx = seg ? eidx_s : nidx_s;

  // prologue: stage step 0 into Xs[0]; issue prefetch for step 1 (vA)
  {
    int r0 = sidx[srow * 16];
    uint4 v0 = *reinterpret_cast<const uint4*>(sbase + (size_t)r0 * sstride + soff);
    *reinterpret_cast<uint4*>(&Xs[0][srow * 136 + seg * 64 + soff]) = v0;
  }
  uint4 vA;
  {
    int r1 = sidx[srow * 16 + 1];
    vA = *reinterpret_cast<const uint4*>(sbase + (size_t)r1 * sstride + soff);
  }
  __syncthreads();

  for (int t = 0; t < DEG; ++t) {
    const int cur = t & 1, nxt = cur ^ 1;
    // issue prefetch for step t+2 (clamped); consumed next iteration
    int tn = (t + 2 < DEG) ? (t + 2) : (DEG - 1);
    int rn = sidx[srow * 16 + tn];
    uint4 vB = *reinterpret_cast<const uint4*>(sbase + (size_t)rn * sstride + soff);

    floatx4 acc[4][2];
#pragma unroll
    for (int g = 0; g < 4; ++g) { acc[g][0] = make4(bias[g]); acc[g][1] = make4(bias[g]); }
    // ---- half 0 (rows 0-15): x-part then h-part ----
#pragma unroll
    for (int kt = 0; kt < 4; ++kt) {
      bf16x8 a0 = ld8(&Xs[cur][l16 * 136 + kt * 32 + quad * 8]);
#pragma unroll
      for (int g = 0; g < 4; ++g) acc[g][0] = mfma16(a0, wx[g][kt], acc[g][0]);
    }
#pragma unroll
    for (int kt = 0; kt < 4; ++kt) {
      bf16x8 h0 = ld8(&Hs[cur][l16 * 136 + kt * 32 + quad * 8]);
#pragma unroll
      for (int g = 0; g < 4; ++g) acc[g][0] = mfma16(h0, wh[g][kt], acc[g][0]);
    }
    // ---- half 1 (rows 16-31): x-part then h-part ----
#pragma unroll
    for (int kt = 0; kt < 4; ++kt) {
      bf16x8 a1 = ld8(&Xs[cur][(16 + l16) * 136 + kt * 32 + quad * 8]);
#pragma unroll
      for (int g = 0; g < 4; ++g) acc[g][1] = mfma16(a1, wx[g][kt], acc[g][1]);
    }
#pragma unroll
    for (int kt = 0; kt < 4; ++kt) {
      bf16x8 h1 = ld8(&Hs[cur][(16 + l16) * 136 + kt * 32 + quad * 8]);
#pragma unroll
      for (int g = 0; g < 4; ++g) acc[g][1] = mfma16(h1, wh[g][kt], acc[g][1]);
    }

    // gate math (registers only) + write h into NEXT buffer; no barrier before
    // this: wave's own acc dependencies gate it, siblings may still be in MFMA.
#pragma unroll
    for (int hh = 0; hh < 2; ++hh) {
      float hv[4];
#pragma unroll
      for (int rr = 0; rr < 4; ++rr) {
        float gi = acc[0][hh][rr], gf = acc[1][hh][rr];
        float gg = acc[2][hh][rr], go = acc[3][hh][rr];
        // c = sig(f)*c_old + sig(i)*tanh(g), shared-rcp fusion for the product
        float sf = sigf(gf);
        float ei = __expf(-gi);
        float eg = expc(-2.0f * gg);
        float r1 = __builtin_amdgcn_rcpf((1.0f + ei) * (1.0f + eg));
        float c  = __builtin_fmaf(sf, cst[hh][rr], (1.0f - eg) * r1);
        cst[hh][rr] = c;
        // h = sig(o)*tanh(c), same fusion
        float eo = __expf(-go);
        float ec = expc(-2.0f * c);
        float r2 = __builtin_amdgcn_rcpf((1.0f + eo) * (1.0f + ec));
        hv[rr] = (1.0f - ec) * r2;
      }
#pragma unroll
      for (int rp = 0; rp < 2; ++rp) {
        unsigned pk;
        asm("v_cvt_pk_bf16_f32 %0, %1, %2" : "=v"(pk) : "v"(hv[rp * 2]), "v"(hv[rp * 2 + 1]));
        const int r0 = hh * 16 + quad * 4 + rp * 2;
        Hs[nxt][r0 * 136 + wave * 16 + l16] = (u16)pk;
        Hs[nxt][(r0 + 1) * 136 + wave * 16 + l16] = (u16)(pk >> 16);
      }
    }

    // land the prefetched step-t+1 tile (issued last iteration) into next Xs
    if (t + 1 < DEG)
      *reinterpret_cast<uint4*>(&Xs[nxt][srow * 136 + seg * 64 + soff]) = vA;
    vA = vB;
    __syncthreads();   // next-buffers (Hs, Xs) fully written before step t+1 reads
  }

  // readout: out = relu(relu(h) @ Wr.T + br), [32,64]; 8 tiles over 8 waves.
  // final h lives in Hs[0] (t=15 wrote nxt = 0).
  {
    const int rt = wave >> 2, ct = wave & 3;
    floatx4 acc = make4(br[ct * 16 + l16]);
#pragma unroll
    for (int kt = 0; kt < 4; ++kt) {
      bf16x8 a = relu8(ld8(&Hs[0][(rt * 16 + l16) * 136 + kt * 32 + quad * 8]));
      bf16x8 b = ld8(Wr + (ct * 16 + l16) * 128 + kt * 32 + quad * 8);
      acc = mfma16(a, b, acc);
    }
#pragma unroll
    for (int rr = 0; rr < 4; ++rr) {
      int row = base + rt * 16 + quad * 4 + rr;
      if (row < NN) {
        float v = acc[rr] > 0.0f ? acc[rr] : 0.0f;
        aggOut[(size_t)row * 64 + ct * 16 + l16] = f2bf(v);
      }
    }
  }
}

// ---------------- K4: node_out = relu([aggP|hN|aggS] @ Wt_n.T + bt_n) ---------
__global__ __launch_bounds__(256, 4) void k_node_out(
    const u16* aggP, const u16* hN, const u16* aggS,
    const u16* Wt, const float* bt, float* outp) {
  __shared__ __align__(16) u16 Xs[64 * 200];
  const int tid = threadIdx.x;
  const int base = blockIdx.x * 64;
  const u16* segp[3] = {aggP, hN, aggS};
#pragma unroll
  for (int seg = 0; seg < 3; ++seg)
#pragma unroll
    for (int j = 0; j < 2; ++j) {
      int flat = tid + j * 256;             // 64 rows x 8 chunks
      int row = flat >> 3, off = (flat & 7) * 8;
      int gr = base + row; if (gr >= NN) gr = NN - 1;
      uint4 v = *reinterpret_cast<const uint4*>(segp[seg] + (size_t)gr * 64 + off);
      *reinterpret_cast<uint4*>(&Xs[row * 200 + seg * 64 + off]) = v;
    }
  __syncthreads();
  const int wave = tid >> 6, lane = tid & 63, l16 = lane & 15, quad = lane >> 4;
  const int rt = wave;
  floatx4 acc[8];
#pragma unroll
  for (int ct = 0; ct < 8; ++ct) acc[ct] = make4(bt[ct * 16 + l16]);
#pragma unroll
  for (int kt = 0; kt < 6; ++kt) {
    bf16x8 a = ld8(&Xs[(rt * 16 + l16) * 200 + kt * 32 + quad * 8]);
#pragma unroll
    for (int ct = 0; ct < 8; ++ct) {
      bf16x8 b = ld8(Wt + (ct * 16 + l16) * 192 + kt * 32 + quad * 8);
      acc[ct] = mfma16(a, b, acc[ct]);
    }
  }
#pragma unroll
  for (int ct = 0; ct < 8; ++ct)
#pragma unroll
    for (int r = 0; r < 4; ++r) {
      int row = base + rt * 16 + quad * 4 + r;
      if (row < NN) {
        float v = acc[ct][r];
        __builtin_nontemporal_store(v > 0.0f ? v : 0.0f,
                                    &outp[(size_t)row * 128 + ct * 16 + l16]);
      }
    }
}

// ---------------- K5: edge_out = relu([hN[src]|hE|hN[dst]] @ Wt_e.T + bt_e) ---
// hE rows live in the FIRST 128 B of this block's own output slots; all reads
// complete (staged to LDS) before the __syncthreads, then we overwrite in place.
__global__ __launch_bounds__(256, 4) void k_edge_out(
    const u16* hN, const u16* hE, const int* esrc, const int* edst,
    const u16* Wt, const float* bt, float* outp) {
  __shared__ __align__(16) u16 Xs[64 * 200];
  __shared__ int idxs[128];
  const int tid = threadIdx.x;
  const size_t base = (size_t)blockIdx.x * 64;  // exact: 12500*64 == 800000
  if (tid < 64) idxs[tid] = esrc[base + tid];
  else if (tid < 128) idxs[tid] = edst[base + tid - 64];
  __syncthreads();
#pragma unroll
  for (int seg = 0; seg < 3; ++seg)
#pragma unroll
    for (int j = 0; j < 2; ++j) {
      int flat = tid + j * 256;
      int row = flat >> 3, off = (flat & 7) * 8;
      size_t grow;
      const u16* sp;
      if (seg == 0)      { grow = (size_t)idxs[row] * 64;       sp = hN; }
      else if (seg == 1) { grow = (base + row) * 128;           sp = hE; }
      else               { grow = (size_t)idxs[64 + row] * 64;  sp = hN; }
      uint4 v = *reinterpret_cast<const uint4*>(sp + grow + off);
      *reinterpret_cast<uint4*>(&Xs[row * 200 + seg * 64 + off]) = v;
    }
  __syncthreads();
  const int wave = tid >> 6, lane = tid & 63, l16 = lane & 15, quad = lane >> 4;
  const int rt = wave;
  floatx4 acc[4];
#pragma unroll
  for (int ct = 0; ct < 4; ++ct) acc[ct] = make4(bt[ct * 16 + l16]);
#pragma unroll
  for (int kt = 0; kt < 6; ++kt) {
    bf16x8 a = ld8(&Xs[(rt * 16 + l16) * 200 + kt * 32 + quad * 8]);
#pragma unroll
    for (int ct = 0; ct < 4; ++ct) {
      bf16x8 b = ld8(Wt + (ct * 16 + l16) * 192 + kt * 32 + quad * 8);
      acc[ct] = mfma16(a, b, acc[ct]);
    }
  }
#pragma unroll
  for (int ct = 0; ct < 4; ++ct)
#pragma unroll
    for (int r = 0; r < 4; ++r) {
      size_t row = base + rt * 16 + quad * 4 + r;
      float v = acc[ct][r];
      __builtin_nontemporal_store(v > 0.0f ? v : 0.0f,
                                  &outp[row * 64 + ct * 16 + l16]);
    }
}

extern "C" void kernel_launch(void* const* d_in, const int* in_sizes, int n_in,
                              void* d_out, int out_size, void* d_ws, size_t ws_size,
                              hipStream_t stream) {
  (void)in_sizes; (void)n_in; (void)out_size; (void)ws_size;
  const float* node_vecs = (const float*)d_in[0];
  const float* edge_vecs = (const float*)d_in[1];
  const int* pred_node_idx = (const int*)d_in[2];
  const int* pred_edge_idx = (const int*)d_in[3];
  const int* succ_node_idx = (const int*)d_in[4];
  const int* succ_edge_idx = (const int*)d_in[5];
  const int* edge_src = (const int*)d_in[6];
  const int* edge_dst = (const int*)d_in[7];
  const float* Wn = (const float*)d_in[8];
  const float* bn = (const float*)d_in[9];
  const float* We = (const float*)d_in[10];
  const float* be = (const float*)d_in[11];
  const float* Wih_p = (const float*)d_in[12];
  const float* Whh_p = (const float*)d_in[13];
  const float* bih_p = (const float*)d_in[14];
  const float* bhh_p = (const float*)d_in[15];
  const float* Wr_p = (const float*)d_in[16];
  const float* br_p = (const float*)d_in[17];
  const float* Wih_s = (const float*)d_in[18];
  const float* Whh_s = (const float*)d_in[19];
  const float* bih_s = (const float*)d_in[20];
  const float* bhh_s = (const float*)d_in[21];
  const float* Wr_s = (const float*)d_in[22];
  const float* br_s = (const float*)d_in[23];
  const float* Wt_n = (const float*)d_in[24];
  const float* bt_n = (const float*)d_in[25];
  const float* Wt_e = (const float*)d_in[26];
  const float* bt_e = (const float*)d_in[27];

  char* ws = (char*)d_ws;
  u16* wWn   = (u16*)(ws + WS_WN);
  u16* wWe   = (u16*)(ws + WS_WE);
  u16* wWihP = (u16*)(ws + WS_WIH_P);
  u16* wWhhP = (u16*)(ws + WS_WHH_P);
  u16* wWrP  = (u16*)(ws + WS_WR_P);
  u16* wWihS = (u16*)(ws + WS_WIH_S);
  u16* wWhhS = (u16*)(ws + WS_WHH_S);
  u16* wWrS  = (u16*)(ws + WS_WR_S);
  u16* wWtN  = (u16*)(ws + WS_WT_N);
  u16* wWtE  = (u16*)(ws + WS_WT_E);
  float* bsumP = (float*)(ws + WS_BSUM_P);
  float* bsumS = (float*)(ws + WS_BSUM_S);
  u16* hN   = (u16*)(ws + WS_HN);
  u16* aggP = (u16*)(ws + WS_AGGP);
  u16* aggS = (u16*)(ws + WS_AGGS);
  float* outN = (float*)d_out;
  float* outE = outN + (size_t)NN * 128;
  u16* hE = (u16*)outE;    // bf16 rows at stride 128 u16 inside edge_out slots

  k_prep<<<1284, 256, 0, stream>>>(Wn, We, Wih_p, Whh_p, Wr_p, Wih_s, Whh_s, Wr_s,
                                   Wt_n, Wt_e, bih_p, bhh_p, bih_s, bhh_s,
                                   (u16*)ws, bsumP, bsumS);
  k_pre_node<<<782, 256, 0, stream>>>(node_vecs, bn, wWn, hN);
  k_pre_edge<<<12500, 256, 0, stream>>>(edge_vecs, be, wWe, hE);
  dim3 g3(1563, 2, 1);
  k_lstm<<<g3, 512, 0, stream>>>(hN, hE,
                                 pred_node_idx, pred_edge_idx, succ_node_idx, succ_edge_idx,
                                 wWihP, wWhhP, bsumP, wWrP, br_p, aggP,
                                 wWihS, wWhhS, bsumS, wWrS, br_s, aggS);
  k_node_out<<<782, 256, 0, stream>>>(aggP, hN, aggS, wWtN, bt_n, outN);
  k_edge_out<<<12500, 256, 0, stream>>>(hN, hE, edge_src, edge_dst, wWtE, bt_e, outE);
}